// Round 4
// baseline (11687.083 us; speedup 1.0000x reference)
//
#include <hip/hip_runtime.h>
#include <math.h>

// ---------------------------------------------------------------------------
// MGRU (BRITS-style) forward, bf16 MFMA, persistent-loop version.
//   precompute: wconv/aconv/gx/gh/beta big GEMMs (unchanged math).
//   T-loop: ONE persistent kernel, PLAIN launch, 256 blocks x 256 threads
//     (grid == CU count; __launch_bounds__(256,1) + 8.6KB LDS -> all blocks
//     co-resident; hand-rolled sense-reversing gbar, no cooperative launch).
//     phase AB (32 blocks): x_hat GEMM (K=512) -> losses/x_c in LDS (XOR-
//       swizzled) -> z_hat GEMM (K=256) -> c_hat/c_c/out/gib.
//     phase C (256 blocks): fused 6-family GRU GEMM + gate epilogue.
//   LOSS PATH (r1-r3 post-mortem): plain stores ONLY, reduced in a SEPARATE
//   trailing dispatch (cross-dispatch coherence is unconditional — the
//   mechanism the 5413us baseline proved). No atomics anywhere in loss path;
//   no cooperative launch anywhere.
// ---------------------------------------------------------------------------

#define F 256
#define H 512
#define B 512
#define T 128
#define TF 32768          // T*F
#define S3TF 98304        // 3*T*F
#define BTF ((size_t)B * T * F)
#define NBLK 256

typedef __attribute__((ext_vector_type(8))) short bf8;
typedef __attribute__((ext_vector_type(4))) float f4;
#define MFMA16 __builtin_amdgcn_mfma_f32_16x16x32_bf16

__device__ inline short f2bf(float x) {
    unsigned u = __builtin_bit_cast(unsigned, x);
    u += 0x7fff + ((u >> 16) & 1);
    return (short)(u >> 16);
}
__device__ inline float bf2f(short s) {
    unsigned u = ((unsigned)(unsigned short)s) << 16;
    return __builtin_bit_cast(float, u);
}
__device__ inline float wsum(float v) {
#pragma unroll
    for (int o = 32; o > 0; o >>= 1) v += __shfl_down(v, o, 64);
    return v;
}

// ------------------------------------------------ device-wide barrier
__device__ inline void gbar(unsigned* cnt, unsigned* gen) {
    __syncthreads();
    if (threadIdx.x == 0) {
        unsigned g = __hip_atomic_load(gen, __ATOMIC_RELAXED, __HIP_MEMORY_SCOPE_AGENT);
        __threadfence();   // release: publish this block's writes
        unsigned a = __hip_atomic_fetch_add(cnt, 1u, __ATOMIC_ACQ_REL, __HIP_MEMORY_SCOPE_AGENT);
        if (a == NBLK - 1) {
            __hip_atomic_store(cnt, 0u, __ATOMIC_RELAXED, __HIP_MEMORY_SCOPE_AGENT);
            __hip_atomic_store(gen, g + 1u, __ATOMIC_RELEASE, __HIP_MEMORY_SCOPE_AGENT);
        } else {
            while (__hip_atomic_load(gen, __ATOMIC_RELAXED, __HIP_MEMORY_SCOPE_AGENT) == g)
                __builtin_amdgcn_s_sleep(1);
        }
        __threadfence();   // acquire: invalidate stale caches
    }
    __syncthreads();
}

// --------------------------------------------------------------------- init
__global__ void init_k(float* __restrict__ hf, short* __restrict__ hb,
                       unsigned* __restrict__ bar) {
    int i = blockIdx.x * 256 + threadIdx.x;   // 262144 = B*H
    hf[i] = 0.f; hb[i] = 0;
    if (blockIdx.x == 0 && threadIdx.x < 32) bar[threadIdx.x] = 0u;
}

// ------------------------------------------------------- weight conversion
__global__ void wconv_k(const float* __restrict__ Wdx, const float* __restrict__ Wdh,
                        const float* __restrict__ Wz, const float* __restrict__ Wout,
                        const float* __restrict__ Wbeta, const float* __restrict__ Wih,
                        const float* __restrict__ Whh, short* __restrict__ wb) {
    int i = blockIdx.x * 256 + threadIdx.x;   // 2097152 total
    float v;
    if (i < 65536) v = Wdx[i];
    else if (i < 196608) v = Wdh[i - 65536];
    else if (i < 262144) { int l = i - 196608; v = ((l >> 8) == (l & 255)) ? 0.f : Wz[l]; }
    else if (i < 393216) v = Wout[i - 262144];
    else if (i < 524288) v = Wbeta[i - 393216];
    else if (i < 1310720) v = Wih[i - 524288];
    else v = Whh[i - 1310720];
    wb[i] = f2bf(v);
}

// --------------------------------------- activation conversion + den partials
__global__ void aconv_k(const float* __restrict__ inp, short* __restrict__ dbf,
                        short* __restrict__ abf, float* __restrict__ denP) {
    int i = blockIdx.x * 256 + threadIdx.x;   // 16777216 ; block = one (t,b) row
    int r = i >> 8, f = i & 255;
    int t = r >> 9, b = r & 511;
    const float* base = inp + (size_t)b * S3TF + (size_t)t * F;
    dbf[i] = f2bf(base[TF + f]);
    float m = base[2 * TF + f];
    abf[(size_t)r * 512 + 256 + f] = f2bf(m);   // m half of [gamma_x | m]
    float s = wsum(m);
    __shared__ float red[4];
    if ((threadIdx.x & 63) == 0) red[threadIdx.x >> 6] = s;
    __syncthreads();
    if (threadIdx.x == 0) denP[r] = red[0] + red[1] + red[2] + red[3];  // plain store
}

// ---------------------------------- precompute GEMMs (M=65536 rows, no LDS)
__global__ __launch_bounds__(256) void gx_gemm(const short* __restrict__ A,
                                               const short* __restrict__ W,
                                               const float* __restrict__ bias,
                                               short* __restrict__ abf) {
    int gw = blockIdx.x * 4 + (threadIdx.x >> 6);   // 65536 wave-tiles
    int lane = threadIdx.x & 63, l16 = lane & 15, quad = lane >> 4;
    int r0 = (gw >> 4) * 16, n0 = (gw & 15) * 16;
    const short* ar = A + (size_t)(r0 + l16) * 256 + quad * 8;
    const short* br = W + (size_t)(n0 + l16) * 256 + quad * 8;
    f4 acc = {};
#pragma unroll
    for (int k = 0; k < 256; k += 32)
        acc = MFMA16(*(const bf8*)(ar + k), *(const bf8*)(br + k), acc, 0, 0, 0);
    int n = n0 + l16;
    float bs = bias[n];
#pragma unroll
    for (int r = 0; r < 4; r++) {
        int row = r0 + quad * 4 + r;
        abf[(size_t)row * 512 + n] = f2bf(expf(-fmaxf(acc[r] + bs, 0.f)));
    }
}

__global__ __launch_bounds__(256) void gh_gemm(const short* __restrict__ A,
                                               const short* __restrict__ W,
                                               const float* __restrict__ bias,
                                               short* __restrict__ ghb) {
    int gw = blockIdx.x * 4 + (threadIdx.x >> 6);   // 131072 wave-tiles
    int lane = threadIdx.x & 63, l16 = lane & 15, quad = lane >> 4;
    int r0 = (gw >> 5) * 16, n0 = (gw & 31) * 16;
    const short* ar = A + (size_t)(r0 + l16) * 256 + quad * 8;
    const short* br = W + (size_t)(n0 + l16) * 256 + quad * 8;
    f4 acc = {};
#pragma unroll
    for (int k = 0; k < 256; k += 32)
        acc = MFMA16(*(const bf8*)(ar + k), *(const bf8*)(br + k), acc, 0, 0, 0);
    int n = n0 + l16;
    float bs = bias[n];
#pragma unroll
    for (int r = 0; r < 4; r++) {
        int row = r0 + quad * 4 + r;
        ghb[(size_t)row * 512 + n] = f2bf(expf(-fmaxf(acc[r] + bs, 0.f)));
    }
}

__global__ __launch_bounds__(256) void beta_gemm(const short* __restrict__ A,
                                                 const short* __restrict__ W,
                                                 const float* __restrict__ bias,
                                                 short* __restrict__ betab) {
    int gw = blockIdx.x * 4 + (threadIdx.x >> 6);   // 65536 wave-tiles, K=512
    int lane = threadIdx.x & 63, l16 = lane & 15, quad = lane >> 4;
    int r0 = (gw >> 4) * 16, n0 = (gw & 15) * 16;
    const short* ar = A + (size_t)(r0 + l16) * 512 + quad * 8;
    const short* br = W + (size_t)(n0 + l16) * 512 + quad * 8;
    f4 acc = {};
#pragma unroll
    for (int k = 0; k < 512; k += 32)
        acc = MFMA16(*(const bf8*)(ar + k), *(const bf8*)(br + k), acc, 0, 0, 0);
    int n = n0 + l16;
    float bs = bias[n];
#pragma unroll
    for (int r = 0; r < 4; r++) {
        int row = r0 + quad * 4 + r;
        betab[(size_t)row * 256 + n] = f2bf(acc[r] + bs);
    }
}

// ----------------------------------------------- persistent T-loop kernel
struct LoopArgs {
    const float* inp;
    const short* Woutb; const float* bout;
    const short* Wzmb;  const float* bz;
    const short* betab; const short* abf; const short* ghb;
    const short* Wihb;  const short* Whhb;
    const float* bih;   const float* bhh;
    short* gib;                    // [B,256] c_c bf16
    float* out;                    // c_hat | c_c | loss
    float* lossP;                  // [T][32][3] per-(t,block) loss partials
    short* hbA; short* hbB;
    float* hfA; float* hfB;
    unsigned* bar;
};

__global__ __launch_bounds__(256, 1) void loop_k(LoopArgs P) {
    const int bc = blockIdx.x;
    const int tid = threadIdx.x;
    const int w = tid >> 6;
    const int lane = tid & 63;
    const int l16 = lane & 15;
    const int quad = lane >> 4;

    __shared__ short xcs[16 * 256];        // swizzled x_c tile (AB blocks)
    __shared__ float redl[3][4];

    const int jt = bc & 31, bg = bc >> 5;
    const int j0 = jt * 16;
    const int b0c = (bg * 4 + w) * 16;

#pragma unroll 1
    for (int t = 0; t < T; ++t) {
        const short* hbc = (t & 1) ? P.hbB : P.hbA;
        short* hbn = (t & 1) ? P.hbA : P.hbB;
        const float* hfc = (t & 1) ? P.hfB : P.hfA;
        float* hfn = (t & 1) ? P.hfA : P.hfB;

        // ============================ phase AB: x_hat -> x_c -> z_hat -> c_c
        if (bc < 32) {
            const int b0 = bc * 16;
            // ---- GEMM1: x_hat[16][256] = hid[16][512] @ Wout^T
            f4 acc1[4] = {};
            const short* ar = hbc + (size_t)(b0 + l16) * 512 + quad * 8;
#pragma unroll
            for (int k = 0; k < 512; k += 32) {
                bf8 a = *(const bf8*)(ar + k);
#pragma unroll
                for (int nt = 0; nt < 4; nt++) {
                    const short* wp = P.Woutb + (size_t)((w * 4 + nt) * 16 + l16) * 512 + quad * 8 + k;
                    acc1[nt] = MFMA16(a, *(const bf8*)wp, acc1[nt], 0, 0, 0);
                }
            }
            float l1 = 0.f;
            f4 xhv[4], vv[4], mm[4];
#pragma unroll
            for (int nt = 0; nt < 4; nt++) {
                int n = (w * 4 + nt) * 16 + l16;
                float bs = P.bout[n];
#pragma unroll
                for (int r = 0; r < 4; r++) {
                    int b = b0 + quad * 4 + r;
                    const float* vb = P.inp + (size_t)b * S3TF + (size_t)t * F + n;
                    float v = vb[0], m = vb[2 * TF];
                    float xh = acc1[nt][r] + bs;
                    l1 += fabsf(v - xh) * m;
                    float xc = m * v + (1.f - m) * xh;
                    int row = quad * 4 + r;
                    *(short*)((char*)xcs + (row << 9) + (((unsigned)(n * 2)) ^ ((row & 7) << 4))) = f2bf(xc);
                    xhv[nt][r] = xh; vv[nt][r] = v; mm[nt][r] = m;
                }
            }
            __syncthreads();
            // ---- GEMM2: z_hat[16][256] = x_c[16][256] @ Wzm^T
            f4 acc2[4] = {};
#pragma unroll
            for (int k = 0; k < 256; k += 32) {
                bf8 a = *(const bf8*)((char*)xcs + (l16 << 9) +
                                      (((unsigned)((k + quad * 8) * 2)) ^ ((l16 & 7) << 4)));
#pragma unroll
                for (int nt = 0; nt < 4; nt++) {
                    const short* wp = P.Wzmb + (size_t)((w * 4 + nt) * 16 + l16) * 256 + quad * 8 + k;
                    acc2[nt] = MFMA16(a, *(const bf8*)wp, acc2[nt], 0, 0, 0);
                }
            }
            float l2 = 0.f, l3 = 0.f;
#pragma unroll
            for (int nt = 0; nt < 4; nt++) {
                int n = (w * 4 + nt) * 16 + l16;
                float bs = P.bz[n];
#pragma unroll
                for (int r = 0; r < 4; r++) {
                    int b = b0 + quad * 4 + r;
                    float zh = acc2[nt][r] + bs;
                    float bt = bf2f(P.betab[((size_t)t * 512 + b) * 256 + n]);
                    float xh = xhv[nt][r];
                    float ch = bt * zh + (1.f - bt) * xh;
                    float m = mm[nt][r], v = vv[nt][r];
                    float cc = m * v + (1.f - m) * ch;
                    P.out[(size_t)b * TF + (size_t)t * F + n] = ch;
                    P.out[BTF + (size_t)b * TF + (size_t)t * F + n] = cc;
                    P.gib[(size_t)b * 256 + n] = f2bf(cc);
                    l2 += fabsf(v - zh) * m;
                    l3 += fabsf(v - ch) * m;
                }
            }
            l1 = wsum(l1); l2 = wsum(l2); l3 = wsum(l3);
            if (lane == 0) { redl[0][w] = l1; redl[1][w] = l2; redl[2][w] = l3; }
            __syncthreads();
            if (tid == 0) {                              // PLAIN stores, no atomics
                float* lp = P.lossP + ((size_t)t * 32 + bc) * 3;
                lp[0] = redl[0][0] + redl[0][1] + redl[0][2] + redl[0][3];
                lp[1] = redl[1][0] + redl[1][1] + redl[1][2] + redl[1][3];
                lp[2] = redl[2][0] + redl[2][1] + redl[2][2] + redl[2][3];
            }
        }
        gbar(P.bar, P.bar + 16);

        // ============================ phase C: fused 6-family GRU + update
        {
            f4 aglr = {}, aglz = {}, agln = {}, ahlr = {}, ahlz = {}, ahln = {};
            const short* ag = P.gib + (size_t)(b0c + l16) * 256 + quad * 8;
            const short* am = P.abf + ((size_t)t * 512 + b0c + l16) * 512 + quad * 8;
            const short* ah = hbc + (size_t)(b0c + l16) * 512 + quad * 8;
            const short* w0 = P.Wihb + (size_t)(j0 + l16) * 512 + quad * 8;
            const short* w3 = P.Whhb + (size_t)(j0 + l16) * 512 + quad * 8;
#pragma unroll
            for (int k = 0; k < 256; k += 32) {
                bf8 g = *(const bf8*)(ag + k);
                bf8 h = *(const bf8*)(ah + k);
                aglr = MFMA16(g, *(const bf8*)(w0 + k), aglr, 0, 0, 0);
                aglz = MFMA16(g, *(const bf8*)(w0 + 512 * 512 + k), aglz, 0, 0, 0);
                agln = MFMA16(g, *(const bf8*)(w0 + 1024 * 512 + k), agln, 0, 0, 0);
                ahlr = MFMA16(h, *(const bf8*)(w3 + k), ahlr, 0, 0, 0);
                ahlz = MFMA16(h, *(const bf8*)(w3 + 512 * 512 + k), ahlz, 0, 0, 0);
                ahln = MFMA16(h, *(const bf8*)(w3 + 1024 * 512 + k), ahln, 0, 0, 0);
            }
#pragma unroll
            for (int k = 256; k < 512; k += 32) {           // m-half aliased from abf
                bf8 g = *(const bf8*)(am + k);
                bf8 h = *(const bf8*)(ah + k);
                aglr = MFMA16(g, *(const bf8*)(w0 + k), aglr, 0, 0, 0);
                aglz = MFMA16(g, *(const bf8*)(w0 + 512 * 512 + k), aglz, 0, 0, 0);
                agln = MFMA16(g, *(const bf8*)(w0 + 1024 * 512 + k), agln, 0, 0, 0);
                ahlr = MFMA16(h, *(const bf8*)(w3 + k), ahlr, 0, 0, 0);
                ahlz = MFMA16(h, *(const bf8*)(w3 + 512 * 512 + k), ahlz, 0, 0, 0);
                ahln = MFMA16(h, *(const bf8*)(w3 + 1024 * 512 + k), ahln, 0, 0, 0);
            }
            int j = j0 + l16;
            float br_ = P.bih[j], bzg = P.bih[512 + j], bn_ = P.bih[1024 + j];
            float cr_ = P.bhh[j], czg = P.bhh[512 + j], cn_ = P.bhh[1024 + j];
#pragma unroll
            for (int r = 0; r < 4; r++) {
                int b = b0c + quad * 4 + r;
                float rg = 1.f / (1.f + expf(-(aglr[r] + br_ + ahlr[r] + cr_)));
                float zg = 1.f / (1.f + expf(-(aglz[r] + bzg + ahlz[r] + czg)));
                float ng = tanhf(agln[r] + bn_ + rg * (ahln[r] + cn_));
                float hold = hfc[(size_t)b * 512 + j];
                float hn = (1.f - zg) * ng + zg * hold;
                if (t + 1 < T) hn *= bf2f(P.ghb[((size_t)(t + 1) * 512 + b) * 512 + j]);
                hfn[(size_t)b * 512 + j] = hn;
                hbn[(size_t)b * 512 + j] = f2bf(hn);
            }
        }
        gbar(P.bar, P.bar + 16);
    }
}

// ------------------------- final loss (separate dispatch: cross-dispatch
// coherence is unconditional; this is the baseline-proven mechanism)
__global__ void final2_k(const float* __restrict__ lossP,
                         const float* __restrict__ denP,
                         float* __restrict__ outloss) {
    int tid = threadIdx.x;   // 128, one per t
    float n = 0.f;
    for (int blk = 0; blk < 32; ++blk) {
        const float* lp = lossP + ((size_t)tid * 32 + blk) * 3;
        n += lp[0] + lp[1] + lp[2];
    }
    float d = 0.f;
    const float* dp = denP + (size_t)tid * 512;
    for (int b = 0; b < 512; ++b) d += dp[b];
    __shared__ float red[128];
    red[tid] = n / (d + 1e-5f);
    __syncthreads();
    for (int o = 64; o > 0; o >>= 1) { if (tid < o) red[tid] += red[tid + o]; __syncthreads(); }
    if (tid == 0) *outloss = red[0];
}

// ---------------------------------------------------------------------------
extern "C" void kernel_launch(void* const* d_in, const int* in_sizes, int n_in,
                              void* d_out, int out_size, void* d_ws, size_t ws_size,
                              hipStream_t stream) {
    const float* inp   = (const float*)d_in[0];
    const float* Wdx   = (const float*)d_in[1];
    const float* bdx   = (const float*)d_in[2];
    const float* Wdh   = (const float*)d_in[3];
    const float* bdh   = (const float*)d_in[4];
    const float* Wout  = (const float*)d_in[5];
    const float* bout  = (const float*)d_in[6];
    const float* Wz    = (const float*)d_in[7];
    const float* bz    = (const float*)d_in[8];
    const float* Wbeta = (const float*)d_in[9];
    const float* bbeta = (const float*)d_in[10];
    const float* Wih   = (const float*)d_in[11];
    const float* Whh   = (const float*)d_in[12];
    const float* bih   = (const float*)d_in[13];
    const float* bhh   = (const float*)d_in[14];
    float* out = (float*)d_out;

    char* p = (char*)d_ws;
    short* wb    = (short*)p; p += (size_t)2097152 * 2;      // all weights bf16
    short* dbf   = (short*)p; p += (size_t)16777216 * 2;     // delta bf16 [T*B,256]
    short* abf   = (short*)p; p += (size_t)33554432 * 2;     // [gamma_x | m] [T*B,512]
    short* ghb   = (short*)p; p += (size_t)33554432 * 2;     // gamma_h bf16 [T*B,512]
    short* betab = (short*)p; p += (size_t)16777216 * 2;     // beta bf16 [T*B,256]
    short* gib   = (short*)p; p += (size_t)131072 * 2;       // c_c bf16 [B,256]
    short* hbA   = (short*)p; p += (size_t)262144 * 2;
    short* hbB   = (short*)p; p += (size_t)262144 * 2;
    float* hfA   = (float*)p; p += (size_t)262144 * 4;
    float* hfB   = (float*)p; p += (size_t)262144 * 4;
    float* lossP = (float*)p; p += (size_t)12288 * 4;        // [T][32][3]
    float* denP  = (float*)p; p += (size_t)65536 * 4;        // [T*512]
    unsigned* bar = (unsigned*)p; p += (size_t)64 * 4;       // cnt @0, gen @16

    const short* Wdxb   = wb;
    const short* Wdhb   = wb + 65536;
    const short* Wzmb   = wb + 196608;
    const short* Woutb  = wb + 262144;
    const short* Wbetab = wb + 393216;
    const short* Wihb   = wb + 524288;
    const short* Whhb   = wb + 1310720;

    init_k<<<1024, 256, 0, stream>>>(hfA, hbA, bar);
    wconv_k<<<8192, 256, 0, stream>>>(Wdx, Wdh, Wz, Wout, Wbeta, Wih, Whh, wb);
    aconv_k<<<65536, 256, 0, stream>>>(inp, dbf, abf, denP);
    gx_gemm<<<16384, 256, 0, stream>>>(dbf, Wdxb, bdx, abf);
    gh_gemm<<<32768, 256, 0, stream>>>(dbf, Wdhb, bdh, ghb);
    beta_gemm<<<16384, 256, 0, stream>>>(abf, Wbetab, bbeta, betab);

    LoopArgs la;
    la.inp = inp; la.Woutb = Woutb; la.bout = bout;
    la.Wzmb = Wzmb; la.bz = bz;
    la.betab = betab; la.abf = abf; la.ghb = ghb;
    la.Wihb = Wihb; la.Whhb = Whhb; la.bih = bih; la.bhh = bhh;
    la.gib = gib; la.out = out; la.lossP = lossP;
    la.hbA = hbA; la.hbB = hbB; la.hfA = hfA; la.hfB = hfB;
    la.bar = bar;
    loop_k<<<NBLK, 256, 0, stream>>>(la);
    final2_k<<<1, 128, 0, stream>>>(lossP, denP, out + 2 * BTF);
}

// Round 6
// 9745.087 us; speedup vs baseline: 1.1993x; 1.1993x over previous
//
#include <hip/hip_runtime.h>
#include <math.h>

// ---------------------------------------------------------------------------
// MGRU (BRITS-style) forward, bf16 MFMA, persistent-loop version.
//   T-loop: ONE persistent kernel, plain launch, 256 blocks x 256 threads.
//   r4 post-mortem: __threadfence() in gbar = full L2 writeback+invalidate
//   per barrier -> 6.8MB/step weight refetch (FETCH_SIZE 867MB) -> 84us/step.
//   Fix: FENCE-FREE barrier. Only cross-block loop data (gib, hb) moves via
//   agent-scope RELAXED atomic loads/stores (sc1: bypass L2, meet at coherent
//   L3 point; no cache maintenance). Release = vmcnt(0) implied by
//   __syncthreads before s_barrier; acquire = sc1 loads issued post-barrier.
//   Weights/betab/ghb/abf/inp stay normally cached => L2-hot for all 128
//   steps. Scattered 2B gib/hb stores become LDS-staged cooperative 8B
//   coherent stores. Loss path: unchanged from r4 (plain stores + separate
//   final2_k dispatch).
//   (r5 was an infra failure — container died before benching; identical
//   source resubmitted after a re-audit found no hang/correctness path.)
// ---------------------------------------------------------------------------

#define F 256
#define H 512
#define B 512
#define T 128
#define TF 32768          // T*F
#define S3TF 98304        // 3*T*F
#define BTF ((size_t)B * T * F)
#define NBLK 256

typedef __attribute__((ext_vector_type(8))) short bf8;
typedef __attribute__((ext_vector_type(4))) float f4;
typedef unsigned long long u64;
#define MFMA16 __builtin_amdgcn_mfma_f32_16x16x32_bf16

__device__ inline short f2bf(float x) {
    unsigned u = __builtin_bit_cast(unsigned, x);
    u += 0x7fff + ((u >> 16) & 1);
    return (short)(u >> 16);
}
__device__ inline float bf2f(short s) {
    unsigned u = ((unsigned)(unsigned short)s) << 16;
    return __builtin_bit_cast(float, u);
}
__device__ inline float wsum(float v) {
#pragma unroll
    for (int o = 32; o > 0; o >>= 1) v += __shfl_down(v, o, 64);
    return v;
}

// ---- coherent (sc1) exchange helpers: bypass L2, no cache maintenance ----
__device__ inline bf8 load16_coh(const short* p) {
    u64 lo = __hip_atomic_load((const u64*)p,       __ATOMIC_RELAXED, __HIP_MEMORY_SCOPE_AGENT);
    u64 hi = __hip_atomic_load(((const u64*)p) + 1, __ATOMIC_RELAXED, __HIP_MEMORY_SCOPE_AGENT);
    struct Pair { u64 lo, hi; } s{lo, hi};
    return __builtin_bit_cast(bf8, s);
}
__device__ inline void store8_coh(short* p, u64 v) {
    __hip_atomic_store((u64*)p, v, __ATOMIC_RELAXED, __HIP_MEMORY_SCOPE_AGENT);
}

// ------------------------------------------------ device-wide barrier
// NO __threadfence: cross-block data goes through sc1 accesses only.
__device__ inline void gbar(unsigned* cnt, unsigned* gen) {
    __syncthreads();   // compiler emits s_waitcnt vmcnt(0) before s_barrier: release
    if (threadIdx.x == 0) {
        unsigned g = __hip_atomic_load(gen, __ATOMIC_RELAXED, __HIP_MEMORY_SCOPE_AGENT);
        unsigned a = __hip_atomic_fetch_add(cnt, 1u, __ATOMIC_RELAXED, __HIP_MEMORY_SCOPE_AGENT);
        if (a == NBLK - 1) {
            __hip_atomic_store(cnt, 0u, __ATOMIC_RELAXED, __HIP_MEMORY_SCOPE_AGENT);
            __hip_atomic_store(gen, g + 1u, __ATOMIC_RELAXED, __HIP_MEMORY_SCOPE_AGENT);
        } else {
            while (__hip_atomic_load(gen, __ATOMIC_RELAXED, __HIP_MEMORY_SCOPE_AGENT) == g)
                __builtin_amdgcn_s_sleep(1);
        }
    }
    __syncthreads();
}

// --------------------------------------------------------------------- init
__global__ void init_k(float* __restrict__ hf, short* __restrict__ hb,
                       unsigned* __restrict__ bar) {
    int i = blockIdx.x * 256 + threadIdx.x;   // 262144 = B*H
    hf[i] = 0.f; hb[i] = 0;
    if (blockIdx.x == 0 && threadIdx.x < 32) bar[threadIdx.x] = 0u;
}

// ------------------------------------------------------- weight conversion
__global__ void wconv_k(const float* __restrict__ Wdx, const float* __restrict__ Wdh,
                        const float* __restrict__ Wz, const float* __restrict__ Wout,
                        const float* __restrict__ Wbeta, const float* __restrict__ Wih,
                        const float* __restrict__ Whh, short* __restrict__ wb) {
    int i = blockIdx.x * 256 + threadIdx.x;   // 2097152 total
    float v;
    if (i < 65536) v = Wdx[i];
    else if (i < 196608) v = Wdh[i - 65536];
    else if (i < 262144) { int l = i - 196608; v = ((l >> 8) == (l & 255)) ? 0.f : Wz[l]; }
    else if (i < 393216) v = Wout[i - 262144];
    else if (i < 524288) v = Wbeta[i - 393216];
    else if (i < 1310720) v = Wih[i - 524288];
    else v = Whh[i - 1310720];
    wb[i] = f2bf(v);
}

// --------------------------------------- activation conversion + den partials
__global__ void aconv_k(const float* __restrict__ inp, short* __restrict__ dbf,
                        short* __restrict__ abf, float* __restrict__ denP) {
    int i = blockIdx.x * 256 + threadIdx.x;   // 16777216 ; block = one (t,b) row
    int r = i >> 8, f = i & 255;
    int t = r >> 9, b = r & 511;
    const float* base = inp + (size_t)b * S3TF + (size_t)t * F;
    dbf[i] = f2bf(base[TF + f]);
    float m = base[2 * TF + f];
    abf[(size_t)r * 512 + 256 + f] = f2bf(m);   // m half of [gamma_x | m]
    float s = wsum(m);
    __shared__ float red[4];
    if ((threadIdx.x & 63) == 0) red[threadIdx.x >> 6] = s;
    __syncthreads();
    if (threadIdx.x == 0) denP[r] = red[0] + red[1] + red[2] + red[3];  // plain store
}

// ---------------------------------- precompute GEMMs (M=65536 rows, no LDS)
__global__ __launch_bounds__(256) void gx_gemm(const short* __restrict__ A,
                                               const short* __restrict__ W,
                                               const float* __restrict__ bias,
                                               short* __restrict__ abf) {
    int gw = blockIdx.x * 4 + (threadIdx.x >> 6);   // 65536 wave-tiles
    int lane = threadIdx.x & 63, l16 = lane & 15, quad = lane >> 4;
    int r0 = (gw >> 4) * 16, n0 = (gw & 15) * 16;
    const short* ar = A + (size_t)(r0 + l16) * 256 + quad * 8;
    const short* br = W + (size_t)(n0 + l16) * 256 + quad * 8;
    f4 acc = {};
#pragma unroll
    for (int k = 0; k < 256; k += 32)
        acc = MFMA16(*(const bf8*)(ar + k), *(const bf8*)(br + k), acc, 0, 0, 0);
    int n = n0 + l16;
    float bs = bias[n];
#pragma unroll
    for (int r = 0; r < 4; r++) {
        int row = r0 + quad * 4 + r;
        abf[(size_t)row * 512 + n] = f2bf(expf(-fmaxf(acc[r] + bs, 0.f)));
    }
}

__global__ __launch_bounds__(256) void gh_gemm(const short* __restrict__ A,
                                               const short* __restrict__ W,
                                               const float* __restrict__ bias,
                                               short* __restrict__ ghb) {
    int gw = blockIdx.x * 4 + (threadIdx.x >> 6);   // 131072 wave-tiles
    int lane = threadIdx.x & 63, l16 = lane & 15, quad = lane >> 4;
    int r0 = (gw >> 5) * 16, n0 = (gw & 31) * 16;
    const short* ar = A + (size_t)(r0 + l16) * 256 + quad * 8;
    const short* br = W + (size_t)(n0 + l16) * 256 + quad * 8;
    f4 acc = {};
#pragma unroll
    for (int k = 0; k < 256; k += 32)
        acc = MFMA16(*(const bf8*)(ar + k), *(const bf8*)(br + k), acc, 0, 0, 0);
    int n = n0 + l16;
    float bs = bias[n];
#pragma unroll
    for (int r = 0; r < 4; r++) {
        int row = r0 + quad * 4 + r;
        ghb[(size_t)row * 512 + n] = f2bf(expf(-fmaxf(acc[r] + bs, 0.f)));
    }
}

__global__ __launch_bounds__(256) void beta_gemm(const short* __restrict__ A,
                                                 const short* __restrict__ W,
                                                 const float* __restrict__ bias,
                                                 short* __restrict__ betab) {
    int gw = blockIdx.x * 4 + (threadIdx.x >> 6);   // 65536 wave-tiles, K=512
    int lane = threadIdx.x & 63, l16 = lane & 15, quad = lane >> 4;
    int r0 = (gw >> 4) * 16, n0 = (gw & 15) * 16;
    const short* ar = A + (size_t)(r0 + l16) * 512 + quad * 8;
    const short* br = W + (size_t)(n0 + l16) * 512 + quad * 8;
    f4 acc = {};
#pragma unroll
    for (int k = 0; k < 512; k += 32)
        acc = MFMA16(*(const bf8*)(ar + k), *(const bf8*)(br + k), acc, 0, 0, 0);
    int n = n0 + l16;
    float bs = bias[n];
#pragma unroll
    for (int r = 0; r < 4; r++) {
        int row = r0 + quad * 4 + r;
        betab[(size_t)row * 256 + n] = f2bf(acc[r] + bs);
    }
}

// ----------------------------------------------- persistent T-loop kernel
struct LoopArgs {
    const float* inp;
    const short* Woutb; const float* bout;
    const short* Wzmb;  const float* bz;
    const short* betab; const short* abf; const short* ghb;
    const short* Wihb;  const short* Whhb;
    const float* bih;   const float* bhh;
    short* gib;                    // [B,256] c_c bf16 (sc1 exchange)
    float* out;                    // c_hat | c_c | loss
    float* lossP;                  // [T][32][3] per-(t,block) loss partials
    short* hbA; short* hbB;        // (sc1 exchange)
    float* hfA; float* hfB;        // block-local, normal cached
    unsigned* bar;
};

__global__ __launch_bounds__(256, 1) void loop_k(LoopArgs P) {
    const int bc = blockIdx.x;
    const int tid = threadIdx.x;
    const int w = tid >> 6;
    const int lane = tid & 63;
    const int l16 = lane & 15;
    const int quad = lane >> 4;

    __shared__ short xcs[16 * 256];        // swizzled x_c tile (AB blocks)
    __shared__ short gcs[16 * 256];        // gib staging tile (AB blocks)
    __shared__ short hcs[64 * 16];         // hb staging tile (C, all blocks)
    __shared__ float redl[3][4];

    const int jt = bc & 31, bg = bc >> 5;
    const int j0 = jt * 16;
    const int b0c = (bg * 4 + w) * 16;

#pragma unroll 1
    for (int t = 0; t < T; ++t) {
        const short* hbc = (t & 1) ? P.hbB : P.hbA;
        short* hbn = (t & 1) ? P.hbA : P.hbB;
        const float* hfc = (t & 1) ? P.hfB : P.hfA;
        float* hfn = (t & 1) ? P.hfA : P.hfB;

        // ============================ phase AB: x_hat -> x_c -> z_hat -> c_c
        if (bc < 32) {
            const int b0 = bc * 16;
            // ---- GEMM1: x_hat[16][256] = hid[16][512] @ Wout^T  (hid via sc1)
            f4 acc1[4] = {};
            const short* ar = hbc + (size_t)(b0 + l16) * 512 + quad * 8;
#pragma unroll
            for (int k = 0; k < 512; k += 32) {
                bf8 a = load16_coh(ar + k);
#pragma unroll
                for (int nt = 0; nt < 4; nt++) {
                    const short* wp = P.Woutb + (size_t)((w * 4 + nt) * 16 + l16) * 512 + quad * 8 + k;
                    acc1[nt] = MFMA16(a, *(const bf8*)wp, acc1[nt], 0, 0, 0);
                }
            }
            float l1 = 0.f;
            f4 xhv[4], vv[4], mm[4];
#pragma unroll
            for (int nt = 0; nt < 4; nt++) {
                int n = (w * 4 + nt) * 16 + l16;
                float bs = P.bout[n];
#pragma unroll
                for (int r = 0; r < 4; r++) {
                    int b = b0 + quad * 4 + r;
                    const float* vb = P.inp + (size_t)b * S3TF + (size_t)t * F + n;
                    float v = vb[0], m = vb[2 * TF];
                    float xh = acc1[nt][r] + bs;
                    l1 += fabsf(v - xh) * m;
                    float xc = m * v + (1.f - m) * xh;
                    int row = quad * 4 + r;
                    *(short*)((char*)xcs + (row << 9) + (((unsigned)(n * 2)) ^ ((row & 7) << 4))) = f2bf(xc);
                    xhv[nt][r] = xh; vv[nt][r] = v; mm[nt][r] = m;
                }
            }
            __syncthreads();
            // ---- GEMM2: z_hat[16][256] = x_c[16][256] @ Wzm^T
            f4 acc2[4] = {};
#pragma unroll
            for (int k = 0; k < 256; k += 32) {
                bf8 a = *(const bf8*)((char*)xcs + (l16 << 9) +
                                      (((unsigned)((k + quad * 8) * 2)) ^ ((l16 & 7) << 4)));
#pragma unroll
                for (int nt = 0; nt < 4; nt++) {
                    const short* wp = P.Wzmb + (size_t)((w * 4 + nt) * 16 + l16) * 256 + quad * 8 + k;
                    acc2[nt] = MFMA16(a, *(const bf8*)wp, acc2[nt], 0, 0, 0);
                }
            }
            float l2 = 0.f, l3 = 0.f;
#pragma unroll
            for (int nt = 0; nt < 4; nt++) {
                int n = (w * 4 + nt) * 16 + l16;
                float bs = P.bz[n];
#pragma unroll
                for (int r = 0; r < 4; r++) {
                    int b = b0 + quad * 4 + r;
                    float zh = acc2[nt][r] + bs;
                    float bt = bf2f(P.betab[((size_t)t * 512 + b) * 256 + n]);
                    float xh = xhv[nt][r];
                    float ch = bt * zh + (1.f - bt) * xh;
                    float m = mm[nt][r], v = vv[nt][r];
                    float cc = m * v + (1.f - m) * ch;
                    P.out[(size_t)b * TF + (size_t)t * F + n] = ch;
                    P.out[BTF + (size_t)b * TF + (size_t)t * F + n] = cc;
                    gcs[((quad * 4 + r) << 8) + n] = f2bf(cc);   // stage for coherent store
                    l2 += fabsf(v - zh) * m;
                    l3 += fabsf(v - ch) * m;
                }
            }
            l1 = wsum(l1); l2 = wsum(l2); l3 = wsum(l3);
            if (lane == 0) { redl[0][w] = l1; redl[1][w] = l2; redl[2][w] = l3; }
            __syncthreads();
            if (tid == 0) {                              // plain stores (r4-proven)
                float* lp = P.lossP + ((size_t)t * 32 + bc) * 3;
                lp[0] = redl[0][0] + redl[0][1] + redl[0][2] + redl[0][3];
                lp[1] = redl[1][0] + redl[1][1] + redl[1][2] + redl[1][3];
                lp[2] = redl[2][0] + redl[2][1] + redl[2][2] + redl[2][3];
            }
            // ---- cooperative coherent gib store: 1024 u64, 4 per thread
#pragma unroll
            for (int q = 0; q < 4; ++q) {
                int u = q * 256 + tid;
                int row = u >> 6, c4 = u & 63;
                store8_coh(P.gib + ((size_t)(b0 + row) * 256 + c4 * 4),
                           ((const u64*)gcs)[u]);
            }
        }
        gbar(P.bar, P.bar + 16);

        // ============================ phase C: fused 6-family GRU + update
        {
            f4 aglr = {}, aglz = {}, agln = {}, ahlr = {}, ahlz = {}, ahln = {};
            const short* ag = P.gib + (size_t)(b0c + l16) * 256 + quad * 8;
            const short* am = P.abf + ((size_t)t * 512 + b0c + l16) * 512 + quad * 8;
            const short* ah = hbc + (size_t)(b0c + l16) * 512 + quad * 8;
            const short* w0 = P.Wihb + (size_t)(j0 + l16) * 512 + quad * 8;
            const short* w3 = P.Whhb + (size_t)(j0 + l16) * 512 + quad * 8;
#pragma unroll
            for (int k = 0; k < 256; k += 32) {
                bf8 g = load16_coh(ag + k);
                bf8 h = load16_coh(ah + k);
                aglr = MFMA16(g, *(const bf8*)(w0 + k), aglr, 0, 0, 0);
                aglz = MFMA16(g, *(const bf8*)(w0 + 512 * 512 + k), aglz, 0, 0, 0);
                agln = MFMA16(g, *(const bf8*)(w0 + 1024 * 512 + k), agln, 0, 0, 0);
                ahlr = MFMA16(h, *(const bf8*)(w3 + k), ahlr, 0, 0, 0);
                ahlz = MFMA16(h, *(const bf8*)(w3 + 512 * 512 + k), ahlz, 0, 0, 0);
                ahln = MFMA16(h, *(const bf8*)(w3 + 1024 * 512 + k), ahln, 0, 0, 0);
            }
#pragma unroll
            for (int k = 256; k < 512; k += 32) {           // m-half aliased from abf
                bf8 g = *(const bf8*)(am + k);
                bf8 h = load16_coh(ah + k);
                aglr = MFMA16(g, *(const bf8*)(w0 + k), aglr, 0, 0, 0);
                aglz = MFMA16(g, *(const bf8*)(w0 + 512 * 512 + k), aglz, 0, 0, 0);
                agln = MFMA16(g, *(const bf8*)(w0 + 1024 * 512 + k), agln, 0, 0, 0);
                ahlr = MFMA16(h, *(const bf8*)(w3 + k), ahlr, 0, 0, 0);
                ahlz = MFMA16(h, *(const bf8*)(w3 + 512 * 512 + k), ahlz, 0, 0, 0);
                ahln = MFMA16(h, *(const bf8*)(w3 + 1024 * 512 + k), ahln, 0, 0, 0);
            }
            int j = j0 + l16;
            float br_ = P.bih[j], bzg = P.bih[512 + j], bn_ = P.bih[1024 + j];
            float cr_ = P.bhh[j], czg = P.bhh[512 + j], cn_ = P.bhh[1024 + j];
#pragma unroll
            for (int r = 0; r < 4; r++) {
                int b = b0c + quad * 4 + r;
                float rg = 1.f / (1.f + expf(-(aglr[r] + br_ + ahlr[r] + cr_)));
                float zg = 1.f / (1.f + expf(-(aglz[r] + bzg + ahlz[r] + czg)));
                float ng = tanhf(agln[r] + bn_ + rg * (ahln[r] + cn_));
                float hold = hfc[(size_t)b * 512 + j];
                float hn = (1.f - zg) * ng + zg * hold;
                if (t + 1 < T) hn *= bf2f(P.ghb[((size_t)(t + 1) * 512 + b) * 512 + j]);
                hfn[(size_t)b * 512 + j] = hn;                 // block-local, cached
                hcs[((w * 16 + quad * 4 + r) << 4) + l16] = f2bf(hn);  // stage
            }
            __syncthreads();
            // ---- cooperative coherent hb store: 256 u64, 1 per thread
            {
                int row = tid >> 2, c4 = tid & 3;
                store8_coh(hbn + ((size_t)(bg * 64 + row) * 512 + j0 + c4 * 4),
                           ((const u64*)hcs)[tid]);
            }
        }
        gbar(P.bar, P.bar + 16);
    }
}

// ------------------------- final loss (separate dispatch; r4-proven)
__global__ void final2_k(const float* __restrict__ lossP,
                         const float* __restrict__ denP,
                         float* __restrict__ outloss) {
    int tid = threadIdx.x;   // 128, one per t
    float n = 0.f;
    for (int blk = 0; blk < 32; ++blk) {
        const float* lp = lossP + ((size_t)tid * 32 + blk) * 3;
        n += lp[0] + lp[1] + lp[2];
    }
    float d = 0.f;
    const float* dp = denP + (size_t)tid * 512;
    for (int b = 0; b < 512; ++b) d += dp[b];
    __shared__ float red[128];
    red[tid] = n / (d + 1e-5f);
    __syncthreads();
    for (int o = 64; o > 0; o >>= 1) { if (tid < o) red[tid] += red[tid + o]; __syncthreads(); }
    if (tid == 0) *outloss = red[0];
}

// ---------------------------------------------------------------------------
extern "C" void kernel_launch(void* const* d_in, const int* in_sizes, int n_in,
                              void* d_out, int out_size, void* d_ws, size_t ws_size,
                              hipStream_t stream) {
    const float* inp   = (const float*)d_in[0];
    const float* Wdx   = (const float*)d_in[1];
    const float* bdx   = (const float*)d_in[2];
    const float* Wdh   = (const float*)d_in[3];
    const float* bdh   = (const float*)d_in[4];
    const float* Wout  = (const float*)d_in[5];
    const float* bout  = (const float*)d_in[6];
    const float* Wz    = (const float*)d_in[7];
    const float* bz    = (const float*)d_in[8];
    const float* Wbeta = (const float*)d_in[9];
    const float* bbeta = (const float*)d_in[10];
    const float* Wih   = (const float*)d_in[11];
    const float* Whh   = (const float*)d_in[12];
    const float* bih   = (const float*)d_in[13];
    const float* bhh   = (const float*)d_in[14];
    float* out = (float*)d_out;

    char* p = (char*)d_ws;
    short* wb    = (short*)p; p += (size_t)2097152 * 2;      // all weights bf16
    short* dbf   = (short*)p; p += (size_t)16777216 * 2;     // delta bf16 [T*B,256]
    short* abf   = (short*)p; p += (size_t)33554432 * 2;     // [gamma_x | m] [T*B,512]
    short* ghb   = (short*)p; p += (size_t)33554432 * 2;     // gamma_h bf16 [T*B,512]
    short* betab = (short*)p; p += (size_t)16777216 * 2;     // beta bf16 [T*B,256]
    short* gib   = (short*)p; p += (size_t)131072 * 2;       // c_c bf16 [B,256]
    short* hbA   = (short*)p; p += (size_t)262144 * 2;
    short* hbB   = (short*)p; p += (size_t)262144 * 2;
    float* hfA   = (float*)p; p += (size_t)262144 * 4;
    float* hfB   = (float*)p; p += (size_t)262144 * 4;
    float* lossP = (float*)p; p += (size_t)12288 * 4;        // [T][32][3]
    float* denP  = (float*)p; p += (size_t)65536 * 4;        // [T*512]
    unsigned* bar = (unsigned*)p; p += (size_t)64 * 4;       // cnt @0, gen @16

    const short* Wdxb   = wb;
    const short* Wdhb   = wb + 65536;
    const short* Wzmb   = wb + 196608;
    const short* Woutb  = wb + 262144;
    const short* Wbetab = wb + 393216;
    const short* Wihb   = wb + 524288;
    const short* Whhb   = wb + 1310720;

    init_k<<<1024, 256, 0, stream>>>(hfA, hbA, bar);
    wconv_k<<<8192, 256, 0, stream>>>(Wdx, Wdh, Wz, Wout, Wbeta, Wih, Whh, wb);
    aconv_k<<<65536, 256, 0, stream>>>(inp, dbf, abf, denP);
    gx_gemm<<<16384, 256, 0, stream>>>(dbf, Wdxb, bdx, abf);
    gh_gemm<<<32768, 256, 0, stream>>>(dbf, Wdhb, bdh, ghb);
    beta_gemm<<<16384, 256, 0, stream>>>(abf, Wbetab, bbeta, betab);

    LoopArgs la;
    la.inp = inp; la.Woutb = Woutb; la.bout = bout;
    la.Wzmb = Wzmb; la.bz = bz;
    la.betab = betab; la.abf = abf; la.ghb = ghb;
    la.Wihb = Wihb; la.Whhb = Whhb; la.bih = bih; la.bhh = bhh;
    la.gib = gib; la.out = out; la.lossP = lossP;
    la.hbA = hbA; la.hbB = hbB; la.hfA = hfA; la.hfB = hfB;
    la.bar = bar;
    loop_k<<<NBLK, 256, 0, stream>>>(la);
    final2_k<<<1, 128, 0, stream>>>(lossP, denP, out + 2 * BTF);
}